// Round 2
// baseline (329.346 us; speedup 1.0000x reference)
//
#include <hip/hip_runtime.h>
#include <hip/hip_bf16.h>
#include <stdint.h>

// FPNAttentionV2 v5: 2 dispatches. (v4 + grid-decode fix: 3201 blocks, x2 = 512 blocks)
//   prep_transpose: weights f32->bf16 frag-major + x1p pad-ring zero + NCHW->NHWC bf16
//   fused_gemm:     512-thread (8-wave) blocks, 128x256 tile (kdown 64x256), full-K LDS
//                   stage with XOR-swizzled (involution, 16B-slot) layout to kill the
//                   8-way LDS bank conflict on A-fragment ds_read_b128.

typedef __attribute__((ext_vector_type(8))) __bf16 bf16x8;
typedef __attribute__((ext_vector_type(4))) float f32x4;
typedef __attribute__((ext_vector_type(8))) unsigned short u16x8;

typedef const __attribute__((address_space(1))) uint32_t* gptr_t;
typedef __attribute__((address_space(3))) uint32_t* lptr_t;

__device__ __forceinline__ void cp16(void* lds, const void* g) {
  // async global->LDS, 16B/lane; LDS dest wave-uniform (HW adds lane*16)
  gptr_t gp = reinterpret_cast<gptr_t>(reinterpret_cast<uintptr_t>(g));
  lptr_t lp = reinterpret_cast<lptr_t>(
      static_cast<uint32_t>(reinterpret_cast<uintptr_t>(lds)));
  __builtin_amdgcn_global_load_lds(gp, lp, 16, 0, 0);
}

// ---------------- prep + transpose merged ----------------
// blocks 0..511:    weights f32 -> bf16 frag-major
// blocks 512..640:  zero x1p pad ring
// blocks 641..2688: x1 NCHW f32 -> NHWC bf16 (padded), 2048 blocks
// blocks 2689..3200: x2 NCHW f32 -> NHWC bf16, 512 blocks
struct WArgs {
  const float* w1[7];
  const float* kdw;  // [256][256][3][3]
};

__global__ void prep_transpose(WArgs a, const float* __restrict__ x1,
                               const float* __restrict__ x2,
                               uint16_t* __restrict__ wf,
                               uint16_t* __restrict__ x1p,
                               uint16_t* __restrict__ x2b) {
  __shared__ float tile[64][65];
  const int bx = blockIdx.x;
  const int tid = threadIdx.x;
  if (bx < 512) {
    // frag-major per matrix (65536 elems): [jg(16)][kc(8)][lane(64)][e(8)]
    //   o = jg*16 + (lane&15), k = kc*32 + (lane>>4)*8 + e
    const int idx = bx * 256 + tid;  // 131072
    const int mat = idx >> 13;
    const int g = idx & 8191;
    const int jg = g >> 9;
    const int kc = (g >> 6) & 7;
    const int lane = g & 63;
    const int o = jg * 16 + (lane & 15);
    const int k0 = kc * 32 + (lane >> 4) * 8;
    float f[8];
    if (mat < 7) {
      const float* w = a.w1[mat];
      const float4 v0 = *(const float4*)(w + o * 256 + k0);
      const float4 v1 = *(const float4*)(w + o * 256 + k0 + 4);
      f[0] = v0.x; f[1] = v0.y; f[2] = v0.z; f[3] = v0.w;
      f[4] = v1.x; f[5] = v1.y; f[6] = v1.z; f[7] = v1.w;
    } else {
      const int tap = mat - 7;
#pragma unroll
      for (int e = 0; e < 8; e++)
        f[e] = a.kdw[(long)o * 2304 + (long)(k0 + e) * 9 + tap];
    }
    u16x8 u;
#pragma unroll
    for (int e = 0; e < 8; e++) {
      __hip_bfloat16 hb = __float2bfloat16(f[e]);
      u[e] = *reinterpret_cast<uint16_t*>(&hb);
    }
    *(u16x8*)(wf + (long)idx * 8) = u;
    return;
  }
  if (bx < 641) {
    // zero the pad ring of x1p [2][130][130][256]; 33024 16B-chunks
    const int c = (bx - 512) * 256 + tid;
    const int b = (c >= 16512) ? 1 : 0;
    const int cc = c - b * 16512;
    int h, w, g8;
    if (cc < 4160) {
      h = 0; w = cc >> 5; g8 = cc & 31;
    } else if (cc < 8320) {
      const int s = cc - 4160; h = 129; w = s >> 5; g8 = s & 31;
    } else if (cc < 12416) {
      const int s = cc - 8320; h = 1 + (s >> 5); w = 0; g8 = s & 31;
    } else {
      const int s = cc - 12416; h = 1 + (s >> 5); w = 129; g8 = s & 31;
    }
    u16x8 z = {};
    *(u16x8*)(x1p + (((long)(b * 130 + h)) * 130 + w) * 256 + g8 * 8) = z;
    return;
  }
  // ---- transpose: NCHW f32 -> NHWC bf16 ----
  const int t = bx - 641;  // 0..2559
  const float* src;
  uint16_t* dst;
  int H, W, pad, b, h, bxx, by;
  if (t < 2048) {
    src = x1; dst = x1p; H = 128; W = 128; pad = 1;
    bxx = t & 1; by = (t >> 1) & 3;
    const int z = t >> 3; b = z >> 7; h = z & 127;
  } else {
    const int t2 = t - 2048;  // 0..511
    src = x2; dst = x2b; H = 64; W = 64; pad = 0;
    bxx = 0; by = t2 & 3;
    const int z = t2 >> 2;  // 0..127
    b = z >> 6; h = z & 63;
  }
  const int wt = bxx * 64;
  const int ct = by * 64;
  const long cs = (long)H * W;
  const float* s = src + ((long)(b * 256 + ct) * H + h) * W + wt;
  const int rw = tid >> 4;
  const int rf = tid & 15;
#pragma unroll
  for (int p = 0; p < 4; p++) {
    const int cl = p * 16 + rw;
    const float4 v = *(const float4*)(s + (long)cl * cs + rf * 4);
    tile[cl][rf * 4 + 0] = v.x;
    tile[cl][rf * 4 + 1] = v.y;
    tile[cl][rf * 4 + 2] = v.z;
    tile[cl][rf * 4 + 3] = v.w;
  }
  __syncthreads();
  const int wl0 = tid >> 3;
  const int cg = tid & 7;
  const int Wp = W + 2 * pad;
  const long rowb = ((long)(b * (H + 2 * pad) + h + pad)) * Wp + pad + wt;
#pragma unroll
  for (int p = 0; p < 2; p++) {
    const int wl = p * 32 + wl0;
    u16x8 u;
#pragma unroll
    for (int k = 0; k < 8; k++) {
      __hip_bfloat16 hb = __float2bfloat16(tile[cg * 8 + k][wl]);
      u[k] = *reinterpret_cast<uint16_t*>(&hb);
    }
    *(u16x8*)(dst + (rowb + wl) * 256 + ct + cg * 8) = u;
  }
}

// ---------------- fused GEMM ----------------
struct Job {
  const uint16_t* A;
  const uint16_t* Wf;
  const float* bias;
  float* out;
  int start;  // first flat block id
  int mode;   // 0: x1 1x1, 1: x2 1x1, 2: x2 + 2x upsample, 3: kdown 3x3s2
};
struct JobArgs {
  Job j[8];
};

// 512 threads = 8 waves (2 row-groups x 4 col-groups).
// Modes 0-2: tile 128x256, full K=256 in LDS (64KB), one barrier pair.
// Mode 3:    tile 64x256, 9 taps (K=2304), 32KB stage per tap.
// LDS layout per kc-block: [row][4 x 16B slots], slot XOR-swizzled by (row>>1)&3
// (involution on byte bits 4-5 vs 7-8; bit 6 untouched). Stage keeps LDS dest
// linear (global_load_lds requirement) and pre-swizzles the GLOBAL k-offset;
// ds_read applies the same XOR -> 2-way (free) instead of 8-way bank conflict.
__global__ __launch_bounds__(512, 4) void fused_gemm(JobArgs args) {
  int jid = 0;
#pragma unroll
  for (int t = 1; t < 8; t++)
    if ((int)blockIdx.x >= args.j[t].start) jid = t;
  const Job jb = args.j[jid];
  const int bid = blockIdx.x - jb.start;
  const int mode = jb.mode;

  __shared__ __align__(16) uint16_t lA[32768];  // 64KB

  const int tid = threadIdx.x;
  const int lane = tid & 63;
  const int wave = tid >> 6;  // 0..7
  const int wr = wave >> 2;   // 0..1 (output row half)
  const int wc = wave & 3;    // 0..3 (output col quarter)
  const int q = lane >> 4;
  const int l15 = lane & 15;
  // stage-side swizzled k-slot select (elems): (lane&3) ^ sw(stage_row)
  const int ksel = ((lane & 3) ^ ((lane >> 3) & 3)) * 8;
  // read-side swizzled slot (elems): q ^ sw(frag_row)
  const int qsw = (q ^ ((l15 >> 1) & 3)) * 8;

  if (mode == 3) {
    // ---- kdown: 64x256 tile ----
    const int mtile = bid;
    // stage row within tile: wc*16 + lane>>2 ; k-half from wr
    const int row = mtile * 64 + wc * 16 + (lane >> 2);
    // row = b*4096 + oh*64 + ow -> padded (b, 2oh, 2ow)
    const long p =
        ((long)((row >> 12) * 130 + 2 * ((row >> 6) & 63))) * 130 + 2 * (row & 63);
    const uint16_t* rowA = jb.A + p * 256 + wr * 32 + ksel;

    f32x4 acc[2][4] = {};
    for (int tap = 0; tap < 9; tap++) {
      const int kh = tap / 3;
      const int kw = tap - kh * 3;
      const long aoff = (long)(kh * 130 + kw) * 256;
      const uint16_t* wf = jb.Wf + (long)tap * 65536;
      if (tap) __syncthreads();
#pragma unroll
      for (int kap = 0; kap < 4; kap++)
        cp16(lA + kap * 4096 + wave * 512, rowA + aoff + kap * 64);
      __syncthreads();
#pragma unroll
      for (int kc = 0; kc < 8; kc++) {
        bf16x8 av[2];
#pragma unroll
        for (int i = 0; i < 2; i++)
          av[i] = *(const bf16x8*)(lA + (kc * 64 + wr * 32 + i * 16 + l15) * 32 + qsw);
#pragma unroll
        for (int j = 0; j < 4; j++) {
          const bf16x8 bv = *(const bf16x8*)(
              wf + ((long)(((wc * 4 + j) * 8 + kc) * 64 + lane)) * 8);
#pragma unroll
          for (int i = 0; i < 2; i++)
            acc[i][j] = __builtin_amdgcn_mfma_f32_16x16x32_bf16(av[i], bv,
                                                                acc[i][j], 0, 0, 0);
        }
      }
    }
    const int nb = wc * 64 + l15;
    const int mb = mtile * 64 + wr * 32 + q * 4;
#pragma unroll
    for (int j = 0; j < 4; j++) {
      const int n = nb + j * 16;
      const float bvs = jb.bias[n];
#pragma unroll
      for (int i = 0; i < 2; i++) {
        const int m0 = mb + i * 16;
#pragma unroll
        for (int r = 0; r < 4; r++)
          jb.out[(long)(m0 + r) * 256 + n] = acc[i][j][r] + bvs;
      }
    }
    return;
  }

  // ---- 1x1 convs: tile 128x256, full K staged once ----
  const int mtile = bid;
  {
    const int m = mtile * 128 + wave * 16 + (lane >> 2);
    long p;
    if (mode == 0) {
      p = ((long)((m >> 14) * 130 + ((m >> 7) & 127) + 1)) * 130 + (m & 127) + 1;
    } else {
      p = m;
    }
    const uint16_t* rowA = jb.A + p * 256 + ksel;
    // stage 64KB: [kc(8)][row(128)][4 swizzled 16B slots]
#pragma unroll
    for (int kap = 0; kap < 8; kap++)
      cp16(lA + kap * 4096 + wave * 512, rowA + kap * 32);
  }
  __syncthreads();

  f32x4 acc[4][4] = {};
#pragma unroll
  for (int kc = 0; kc < 8; kc++) {
    bf16x8 av[4];
#pragma unroll
    for (int i = 0; i < 4; i++)
      av[i] = *(const bf16x8*)(lA + (kc * 128 + wr * 64 + i * 16 + l15) * 32 + qsw);
#pragma unroll
    for (int j = 0; j < 4; j++) {
      const bf16x8 bv = *(const bf16x8*)(
          jb.Wf + ((long)(((wc * 4 + j) * 8 + kc) * 64 + lane)) * 8);
#pragma unroll
      for (int i = 0; i < 4; i++)
        acc[i][j] = __builtin_amdgcn_mfma_f32_16x16x32_bf16(av[i], bv,
                                                            acc[i][j], 0, 0, 0);
    }
  }

  // epilogue: C/D layout col=lane&15, row=quad*4+reg
  const int nb = wc * 64 + l15;
  const int mb = mtile * 128 + wr * 64 + q * 4;
  if (mode == 2) {
#pragma unroll
    for (int j = 0; j < 4; j++) {
      const int n = nb + j * 16;
      const float bvs = jb.bias[n];
#pragma unroll
      for (int i = 0; i < 4; i++) {
        const int m0 = mb + i * 16;
#pragma unroll
        for (int r = 0; r < 4; r++) {
          const int m = m0 + r;  // b*4096 + h2*64 + w2
          const int b = m >> 12;
          const int h2 = (m >> 6) & 63;
          const int w2 = m & 63;
          const float val = acc[i][j][r] + bvs;
          float* o =
              jb.out + ((long)(b * 128 + 2 * h2) * 128 + 2 * w2) * 256 + n;
          o[0] = val;
          o[256] = val;
          o[32768] = val;
          o[32768 + 256] = val;
        }
      }
    }
  } else {
#pragma unroll
    for (int j = 0; j < 4; j++) {
      const int n = nb + j * 16;
      const float bvs = jb.bias[n];
#pragma unroll
      for (int i = 0; i < 4; i++) {
        const int m0 = mb + i * 16;
#pragma unroll
        for (int r = 0; r < 4; r++)
          jb.out[(long)(m0 + r) * 256 + n] = acc[i][j][r] + bvs;
      }
    }
  }
}

extern "C" void kernel_launch(void* const* d_in, const int* in_sizes, int n_in,
                              void* d_out, int out_size, void* d_ws,
                              size_t ws_size, hipStream_t stream) {
  (void)in_sizes; (void)n_in; (void)out_size; (void)ws_size;
  const float* x1 = (const float*)d_in[0];
  const float* x2 = (const float*)d_in[1];
  float* out = (float*)d_out;

  uint16_t* x1p = (uint16_t*)d_ws;  // [2][130][130][256] = 8,652,800
  uint16_t* x2b = x1p + 8652800;    // [2][64][64][256]   = 2,097,152
  uint16_t* wf = x2b + 2097152;     // 16 x 65536 frag-major

  WArgs wa;
  wa.w1[0] = (const float*)d_in[2];   // q1_w
  wa.w1[1] = (const float*)d_in[4];   // q2_w
  wa.w1[2] = (const float*)d_in[6];   // ks1_w
  wa.w1[3] = (const float*)d_in[8];   // ks2_w
  wa.w1[4] = (const float*)d_in[10];  // kup_w
  wa.w1[5] = (const float*)d_in[12];  // v1_w
  wa.w1[6] = (const float*)d_in[14];  // v2_w
  wa.kdw = (const float*)d_in[16];    // kdown_w
  prep_transpose<<<3201, 256, 0, stream>>>(wa, x1, x2, wf, x1p, x2b);

  // d_out float offsets (tuple order):
  // q1:0 q2:8388608 k_up:10485760 k_self1:18874368 k_self2:27262976
  // k_down:29360128 v1:31457280 v2:39845888
  JobArgs ja;
  ja.j[0] = {x1p, wf + 7 * 65536, (const float*)d_in[17], out + 29360128L, 0,    3};  // kdown
  ja.j[1] = {x1p, wf + 0 * 65536, (const float*)d_in[3],  out + 0L,        128,  0};  // q1
  ja.j[2] = {x1p, wf + 2 * 65536, (const float*)d_in[7],  out + 18874368L, 384,  0};  // ks1
  ja.j[3] = {x1p, wf + 5 * 65536, (const float*)d_in[13], out + 31457280L, 640,  0};  // v1
  ja.j[4] = {x2b, wf + 4 * 65536, (const float*)d_in[11], out + 10485760L, 896,  2};  // kup
  ja.j[5] = {x2b, wf + 1 * 65536, (const float*)d_in[5],  out + 8388608L,  960,  1};  // q2
  ja.j[6] = {x2b, wf + 3 * 65536, (const float*)d_in[9],  out + 27262976L, 1024, 1};  // ks2
  ja.j[7] = {x2b, wf + 6 * 65536, (const float*)d_in[15], out + 39845888L, 1088, 1};  // v2
  fused_gemm<<<1152, 512, 0, stream>>>(ja);
}

// Round 3
// 291.453 us; speedup vs baseline: 1.1300x; 1.1300x over previous
//
#include <hip/hip_runtime.h>
#include <hip/hip_bf16.h>
#include <stdint.h>

// FPNAttentionV2 v6: 2 dispatches.
//   prep_transpose: weights f32->bf16 frag-major + x1p pad-ring zero + NCHW->NHWC bf16
//   fused_gemm:     v3's proven 256-thread/4-wave structure (128x256 tile, acc[4][8],
//                   256-VGPR regime) + XOR-swizzled LDS slots (involution on 16B slots,
//                   sw(row)=(row>>1)&3) to turn the 8-way A-fragment ds_read_b128 bank
//                   conflict into a free 2-way. Stage keeps LDS dest linear
//                   (global_load_lds requirement) and pre-swizzles the GLOBAL k-chunk.

typedef __attribute__((ext_vector_type(8))) __bf16 bf16x8;
typedef __attribute__((ext_vector_type(4))) float f32x4;
typedef __attribute__((ext_vector_type(8))) unsigned short u16x8;

typedef const __attribute__((address_space(1))) uint32_t* gptr_t;
typedef __attribute__((address_space(3))) uint32_t* lptr_t;

__device__ __forceinline__ void cp16(void* lds, const void* g) {
  // async global->LDS, 16B/lane; LDS dest wave-uniform (HW adds lane*16)
  gptr_t gp = reinterpret_cast<gptr_t>(reinterpret_cast<uintptr_t>(g));
  lptr_t lp = reinterpret_cast<lptr_t>(
      static_cast<uint32_t>(reinterpret_cast<uintptr_t>(lds)));
  __builtin_amdgcn_global_load_lds(gp, lp, 16, 0, 0);
}

// ---------------- prep + transpose merged ----------------
// blocks 0..511:    weights f32 -> bf16 frag-major
// blocks 512..640:  zero x1p pad ring
// blocks 641..2688: x1 NCHW f32 -> NHWC bf16 (padded), 2048 blocks
// blocks 2689..3200: x2 NCHW f32 -> NHWC bf16, 512 blocks
struct WArgs {
  const float* w1[7];
  const float* kdw;  // [256][256][3][3]
};

__global__ void prep_transpose(WArgs a, const float* __restrict__ x1,
                               const float* __restrict__ x2,
                               uint16_t* __restrict__ wf,
                               uint16_t* __restrict__ x1p,
                               uint16_t* __restrict__ x2b) {
  __shared__ float tile[64][65];
  const int bx = blockIdx.x;
  const int tid = threadIdx.x;
  if (bx < 512) {
    // frag-major per matrix (65536 elems): [jg(16)][kc(8)][lane(64)][e(8)]
    //   o = jg*16 + (lane&15), k = kc*32 + (lane>>4)*8 + e
    const int idx = bx * 256 + tid;  // 131072
    const int mat = idx >> 13;
    const int g = idx & 8191;
    const int jg = g >> 9;
    const int kc = (g >> 6) & 7;
    const int lane = g & 63;
    const int o = jg * 16 + (lane & 15);
    const int k0 = kc * 32 + (lane >> 4) * 8;
    float f[8];
    if (mat < 7) {
      const float* w = a.w1[mat];
      const float4 v0 = *(const float4*)(w + o * 256 + k0);
      const float4 v1 = *(const float4*)(w + o * 256 + k0 + 4);
      f[0] = v0.x; f[1] = v0.y; f[2] = v0.z; f[3] = v0.w;
      f[4] = v1.x; f[5] = v1.y; f[6] = v1.z; f[7] = v1.w;
    } else {
      const int tap = mat - 7;
#pragma unroll
      for (int e = 0; e < 8; e++)
        f[e] = a.kdw[(long)o * 2304 + (long)(k0 + e) * 9 + tap];
    }
    u16x8 u;
#pragma unroll
    for (int e = 0; e < 8; e++) {
      __hip_bfloat16 hb = __float2bfloat16(f[e]);
      u[e] = *reinterpret_cast<uint16_t*>(&hb);
    }
    *(u16x8*)(wf + (long)idx * 8) = u;
    return;
  }
  if (bx < 641) {
    // zero the pad ring of x1p [2][130][130][256]; 33024 16B-chunks
    const int c = (bx - 512) * 256 + tid;
    const int b = (c >= 16512) ? 1 : 0;
    const int cc = c - b * 16512;
    int h, w, g8;
    if (cc < 4160) {
      h = 0; w = cc >> 5; g8 = cc & 31;
    } else if (cc < 8320) {
      const int s = cc - 4160; h = 129; w = s >> 5; g8 = s & 31;
    } else if (cc < 12416) {
      const int s = cc - 8320; h = 1 + (s >> 5); w = 0; g8 = s & 31;
    } else {
      const int s = cc - 12416; h = 1 + (s >> 5); w = 129; g8 = s & 31;
    }
    u16x8 z = {};
    *(u16x8*)(x1p + (((long)(b * 130 + h)) * 130 + w) * 256 + g8 * 8) = z;
    return;
  }
  // ---- transpose: NCHW f32 -> NHWC bf16 ----
  const int t = bx - 641;  // 0..2559
  const float* src;
  uint16_t* dst;
  int H, W, pad, b, h, bxx, by;
  if (t < 2048) {
    src = x1; dst = x1p; H = 128; W = 128; pad = 1;
    bxx = t & 1; by = (t >> 1) & 3;
    const int z = t >> 3; b = z >> 7; h = z & 127;
  } else {
    const int t2 = t - 2048;  // 0..511
    src = x2; dst = x2b; H = 64; W = 64; pad = 0;
    bxx = 0; by = t2 & 3;
    const int z = t2 >> 2;  // 0..127
    b = z >> 6; h = z & 63;
  }
  const int wt = bxx * 64;
  const int ct = by * 64;
  const long cs = (long)H * W;
  const float* s = src + ((long)(b * 256 + ct) * H + h) * W + wt;
  const int rw = tid >> 4;
  const int rf = tid & 15;
#pragma unroll
  for (int p = 0; p < 4; p++) {
    const int cl = p * 16 + rw;
    const float4 v = *(const float4*)(s + (long)cl * cs + rf * 4);
    tile[cl][rf * 4 + 0] = v.x;
    tile[cl][rf * 4 + 1] = v.y;
    tile[cl][rf * 4 + 2] = v.z;
    tile[cl][rf * 4 + 3] = v.w;
  }
  __syncthreads();
  const int wl0 = tid >> 3;
  const int cg = tid & 7;
  const int Wp = W + 2 * pad;
  const long rowb = ((long)(b * (H + 2 * pad) + h + pad)) * Wp + pad + wt;
#pragma unroll
  for (int p = 0; p < 2; p++) {
    const int wl = p * 32 + wl0;
    u16x8 u;
#pragma unroll
    for (int k = 0; k < 8; k++) {
      __hip_bfloat16 hb = __float2bfloat16(tile[cg * 8 + k][wl]);
      u[k] = *reinterpret_cast<uint16_t*>(&hb);
    }
    *(u16x8*)(dst + (rowb + wl) * 256 + ct + cg * 8) = u;
  }
}

// ---------------- fused GEMM ----------------
struct Job {
  const uint16_t* A;
  const uint16_t* Wf;
  const float* bias;
  float* out;
  int start;  // first flat block id
  int mode;   // 0: x1 1x1, 1: x2 1x1, 2: x2 + 2x upsample, 3: kdown 3x3s2
};
struct JobArgs {
  Job j[8];
};

// block 256 = 4 waves (2x2). Modes 0-2: tile 128x256, full K=256 in LDS (64KB), one
// barrier pair. Mode 3: tile 64x128, 9 taps (K=2304), 32KB stage per tap.
// LDS rows are 32 elems (4 x 16B slots); slot XOR-swizzled by sw(row)=(row>>1)&3.
// Stage keeps LDS dest linear and pre-swizzles the GLOBAL k-chunk (ksel);
// ds_read applies the same XOR (qsw) -> 2-way (free) instead of 8-way conflict.
__global__ __launch_bounds__(256, 2) void fused_gemm(JobArgs args) {
  int jid = 0;
#pragma unroll
  for (int t = 1; t < 8; t++)
    if ((int)blockIdx.x >= args.j[t].start) jid = t;
  const Job jb = args.j[jid];
  const int bid = blockIdx.x - jb.start;
  const int mode = jb.mode;

  __shared__ __align__(16) uint16_t lA[32768];  // 64KB

  const int tid = threadIdx.x;
  const int lane = tid & 63;
  const int wave = tid >> 6;
  const int wr = wave & 1;
  const int wc = wave >> 1;
  const int q = lane >> 4;
  const int l15 = lane & 15;
  // stage-side swizzled k-chunk select (elems): (lane&3) ^ sw(dest_row)
  //   dest_row = wave*16 + (lane>>2)  ->  sw = ((lane>>3)&3)  (wave*16>>1 ≡ 0 mod 4)
  const int ksel = ((lane & 3) ^ ((lane >> 3) & 3)) * 8;
  // read-side swizzled slot (elems): q ^ sw(frag_row)
  //   frag_row = wr*64 + i*16 + l15  ->  sw = ((l15>>1)&3)  (wr*64, i*16 ≡ 0 mod 8)
  const int qsw = (q ^ ((l15 >> 1) & 3)) * 8;

  if (mode == 3) {
    // ---- kdown: 64x128 tile, mtile = bid>>1, ntile = bid&1 ----
    const int mtile = bid >> 1;
    const int ntile = bid & 1;
    const int row = mtile * 64 + wave * 16 + (lane >> 2);
    // row = b*4096 + oh*64 + ow -> padded (b, 2oh, 2ow)
    const long p =
        ((long)((row >> 12) * 130 + 2 * ((row >> 6) & 63))) * 130 + 2 * (row & 63);
    const uint16_t* rowA = jb.A + p * 256 + ksel;

    f32x4 acc[2][4] = {};
    for (int tap = 0; tap < 9; tap++) {
      const int kh = tap / 3;
      const int kw = tap - kh * 3;
      const long aoff = (long)(kh * 130 + kw) * 256;
      const uint16_t* wf = jb.Wf + (long)tap * 65536;
      if (tap) __syncthreads();
#pragma unroll
      for (int kap = 0; kap < 8; kap++)
        cp16(lA + (kap * 256 + wave * 64) * 8, rowA + aoff + kap * 32);
      __syncthreads();
#pragma unroll
      for (int kc = 0; kc < 8; kc++) {
        bf16x8 av[2];
#pragma unroll
        for (int i = 0; i < 2; i++)
          av[i] = *(const bf16x8*)(lA + (kc * 64 + wr * 32 + i * 16 + l15) * 32 + qsw);
#pragma unroll
        for (int j = 0; j < 4; j++) {
          const bf16x8 bv = *(const bf16x8*)(
              wf + ((long)((ntile * 8 + wc * 4 + j) * 8 + kc) * 64 + lane) * 8);
#pragma unroll
          for (int i = 0; i < 2; i++)
            acc[i][j] = __builtin_amdgcn_mfma_f32_16x16x32_bf16(av[i], bv,
                                                                acc[i][j], 0, 0, 0);
        }
      }
    }
    const int nb = ntile * 128 + wc * 64 + l15;
    const int mb = mtile * 64 + wr * 32 + q * 4;
#pragma unroll
    for (int j = 0; j < 4; j++) {
      const int n = nb + j * 16;
      const float bvs = jb.bias[n];
#pragma unroll
      for (int i = 0; i < 2; i++) {
        const int m0 = mb + i * 16;
#pragma unroll
        for (int r = 0; r < 4; r++)
          jb.out[(long)(m0 + r) * 256 + n] = acc[i][j][r] + bvs;
      }
    }
    return;
  }

  // ---- 1x1 convs: tile 128x256, full K staged once ----
  const int mtile = bid;
  const uint16_t* rowA[2];
  {
    const int rbase = wave * 16 + (lane >> 2);
#pragma unroll
    for (int rh = 0; rh < 2; rh++) {
      const int m = mtile * 128 + rh * 64 + rbase;
      long p;
      if (mode == 0) {
        p = ((long)((m >> 14) * 130 + ((m >> 7) & 127) + 1)) * 130 + (m & 127) + 1;
      } else {
        p = m;
      }
      rowA[rh] = jb.A + p * 256 + ksel;
    }
  }

  // stage 64KB: [kc(8)][row(128)][4 swizzled 16B slots]
#pragma unroll
  for (int kap = 0; kap < 16; kap++)
    cp16(lA + (kap * 256 + wave * 64) * 8, rowA[kap & 1] + (kap >> 1) * 32);
  __syncthreads();

  f32x4 acc[4][8] = {};
#pragma unroll
  for (int kc = 0; kc < 8; kc++) {
    bf16x8 av[4];
#pragma unroll
    for (int i = 0; i < 4; i++)
      av[i] = *(const bf16x8*)(lA + (kc * 128 + wr * 64 + i * 16 + l15) * 32 + qsw);
#pragma unroll
    for (int j = 0; j < 8; j++) {
      const bf16x8 bv =
          *(const bf16x8*)(jb.Wf + ((long)((wc * 8 + j) * 8 + kc) * 64 + lane) * 8);
#pragma unroll
      for (int i = 0; i < 4; i++)
        acc[i][j] = __builtin_amdgcn_mfma_f32_16x16x32_bf16(av[i], bv,
                                                            acc[i][j], 0, 0, 0);
    }
  }

  // epilogue: C/D layout col=lane&15, row=quad*4+reg
  const int nb = wc * 128 + l15;
  const int mb = mtile * 128 + wr * 64 + q * 4;
  if (mode == 2) {
#pragma unroll
    for (int j = 0; j < 8; j++) {
      const int n = nb + j * 16;
      const float bvs = jb.bias[n];
#pragma unroll
      for (int i = 0; i < 4; i++) {
        const int m0 = mb + i * 16;
#pragma unroll
        for (int r = 0; r < 4; r++) {
          const int m = m0 + r;  // b*4096 + h2*64 + w2
          const int b = m >> 12;
          const int h2 = (m >> 6) & 63;
          const int w2 = m & 63;
          const float val = acc[i][j][r] + bvs;
          float* o =
              jb.out + ((long)(b * 128 + 2 * h2) * 128 + 2 * w2) * 256 + n;
          o[0] = val;
          o[256] = val;
          o[32768] = val;
          o[32768 + 256] = val;
        }
      }
    }
  } else {
#pragma unroll
    for (int j = 0; j < 8; j++) {
      const int n = nb + j * 16;
      const float bvs = jb.bias[n];
#pragma unroll
      for (int i = 0; i < 4; i++) {
        const int m0 = mb + i * 16;
#pragma unroll
        for (int r = 0; r < 4; r++)
          jb.out[(long)(m0 + r) * 256 + n] = acc[i][j][r] + bvs;
      }
    }
  }
}

extern "C" void kernel_launch(void* const* d_in, const int* in_sizes, int n_in,
                              void* d_out, int out_size, void* d_ws,
                              size_t ws_size, hipStream_t stream) {
  (void)in_sizes; (void)n_in; (void)out_size; (void)ws_size;
  const float* x1 = (const float*)d_in[0];
  const float* x2 = (const float*)d_in[1];
  float* out = (float*)d_out;

  uint16_t* x1p = (uint16_t*)d_ws;  // [2][130][130][256] = 8,652,800
  uint16_t* x2b = x1p + 8652800;    // [2][64][64][256]   = 2,097,152
  uint16_t* wf = x2b + 2097152;     // 16 x 65536 frag-major

  WArgs wa;
  wa.w1[0] = (const float*)d_in[2];   // q1_w
  wa.w1[1] = (const float*)d_in[4];   // q2_w
  wa.w1[2] = (const float*)d_in[6];   // ks1_w
  wa.w1[3] = (const float*)d_in[8];   // ks2_w
  wa.w1[4] = (const float*)d_in[10];  // kup_w
  wa.w1[5] = (const float*)d_in[12];  // v1_w
  wa.w1[6] = (const float*)d_in[14];  // v2_w
  wa.kdw = (const float*)d_in[16];    // kdown_w
  prep_transpose<<<3201, 256, 0, stream>>>(wa, x1, x2, wf, x1p, x2b);

  // d_out float offsets (tuple order):
  // q1:0 q2:8388608 k_up:10485760 k_self1:18874368 k_self2:27262976
  // k_down:29360128 v1:31457280 v2:39845888
  JobArgs ja;
  ja.j[0] = {x1p, wf + 7 * 65536, (const float*)d_in[17], out + 29360128L, 0,    3};  // kdown
  ja.j[1] = {x1p, wf + 0 * 65536, (const float*)d_in[3],  out + 0L,        256,  0};  // q1
  ja.j[2] = {x1p, wf + 2 * 65536, (const float*)d_in[7],  out + 18874368L, 512,  0};  // ks1
  ja.j[3] = {x1p, wf + 5 * 65536, (const float*)d_in[13], out + 31457280L, 768,  0};  // v1
  ja.j[4] = {x2b, wf + 4 * 65536, (const float*)d_in[11], out + 10485760L, 1024, 2};  // kup
  ja.j[5] = {x2b, wf + 1 * 65536, (const float*)d_in[5],  out + 8388608L,  1088, 1};  // q2
  ja.j[6] = {x2b, wf + 3 * 65536, (const float*)d_in[9],  out + 27262976L, 1152, 1};  // ks2
  ja.j[7] = {x2b, wf + 6 * 65536, (const float*)d_in[15], out + 39845888L, 1216, 1};  // v2
  fused_gemm<<<1280, 256, 0, stream>>>(ja);
}